// Round 11
// baseline (2087.813 us; speedup 1.0000x reference)
//
#include <hip/hip_runtime.h>

// VectorQuantizer: z [16,4096,256] f32, emb [1024,256] f32.
// out = [ z_q (16777216 f32) | loss (1) | indices-as-f32 (65536) ]
//
// Fast f32 pass (8x8 register tile, dbuf chunked LDS) + exact np-chain
// rescore for rows with top-2 gap <= MARGIN. np chain (proven round 7):
// g32 = f32(f64 dot); t = fadd_rn(fsub_rn(sx32, 2*g32), se32[k]); first-min.

constexpr int D      = 256;
constexpr int KC     = 1024;
constexpr int BM     = 128;               // rows per block
constexpr int BN     = 128;               // codes per kt tile
constexpr int DC     = 16;                // dims per chunk
constexpr int PAD    = 132;               // 128+4 floats, 16B-aligned stride
constexpr int NROWS  = 16 * 4096;
constexpr long long ZQ_N = (long long)NROWS * D;
constexpr float MARGIN = 1e-4f;           // flip window ~6.2e-5; 1.6x safety
constexpr int  CAP   = 32768;

// numpy pairwise sum of squares, 128 elems stride s (8-acc base + tree).
__device__ __forceinline__ float np_half_sumsq(const float* a, int s) {
    float r[8];
#pragma unroll
    for (int j = 0; j < 8; ++j) r[j] = __fmul_rn(a[j * s], a[j * s]);
    for (int i = 8; i < 128; i += 8)
#pragma unroll
        for (int j = 0; j < 8; ++j)
            r[j] = __fadd_rn(r[j], __fmul_rn(a[(i + j) * s], a[(i + j) * s]));
    return __fadd_rn(__fadd_rn(__fadd_rn(r[0], r[1]), __fadd_rn(r[2], r[3])),
                     __fadd_rn(__fadd_rn(r[4], r[5]), __fadd_rn(r[6], r[7])));
}
__device__ __forceinline__ float np_sumsq_256(const float* a, int s) {
    return __fadd_rn(np_half_sumsq(a, s), np_half_sumsq(a + 128 * s, s));
}

// ---------------------------------------------------------------- prep ----
__global__ __launch_bounds__(256) void vq_prep(const float* __restrict__ emb,
                                               float* __restrict__ se32,
                                               double* __restrict__ acc,
                                               int* __restrict__ cnt) {
    int k = blockIdx.x * 256 + threadIdx.x;
    if (k < KC) se32[k] = np_sumsq_256(emb + (size_t)k * D, 1);
    if (k == 0) { *acc = 0.0; *cnt = 0; }
}

// ------------------------------------------------------------ fast main ----
__global__ __launch_bounds__(256, 3) void vq_main(const float* __restrict__ z,
                                                  const float* __restrict__ emb,
                                                  const float* __restrict__ se32,
                                                  float* __restrict__ out_zq,
                                                  float* __restrict__ out_idx1,
                                                  float* __restrict__ out_idx2,
                                                  double* __restrict__ acc,
                                                  int* __restrict__ cnt,
                                                  int* __restrict__ rowlist) {
    __shared__ float xs_c[2][DC][PAD];   // 16.9 KB  (z chunk, transposed)
    __shared__ float es_c[2][DC][PAD];   // 16.9 KB  (emb chunk, transposed)
    __shared__ float sxs[BM];
    __shared__ int   code_of_row[BM];

    const int tid = threadIdx.x;
    const int tx  = tid & 15;
    const int ty  = tid >> 4;
    const int r0  = blockIdx.x * BM;

    // np-exact ||x||^2 per row (from global; L2-warming)
    if (tid < BM) sxs[tid] = np_sumsq_256(z + (size_t)(r0 + tid) * D, 1);

    const int scol = tid >> 1;            // 0..127 (row or code within tile)
    const int soff = (tid & 1) * 8;       // dim sub-offset 0 / 8

    // ---- prologue: stage chunk 0 (kt=0, d0=0) ----
    {
        const float* zp = z + (size_t)(r0 + scol) * D + soff;
        float4 a0 = *(const float4*)zp, a1 = *(const float4*)(zp + 4);
        const float* ep = emb + (size_t)scol * D + soff;
        float4 b0 = *(const float4*)ep, b1 = *(const float4*)(ep + 4);
        const float* af = (const float*)&a0; const float* af1 = (const float*)&a1;
        const float* bf = (const float*)&b0; const float* bf1 = (const float*)&b1;
#pragma unroll
        for (int e = 0; e < 4; ++e) {
            xs_c[0][soff + e][scol]     = af[e];
            xs_c[0][soff + 4 + e][scol] = af1[e];
            es_c[0][soff + e][scol]     = bf[e];
            es_c[0][soff + 4 + e][scol] = bf1[e];
        }
    }
    __syncthreads();

    float sxr[8];
#pragma unroll
    for (int i = 0; i < 8; ++i)
        sxr[i] = sxs[(i < 4) ? (ty * 4 + i) : (64 + ty * 4 + i - 4)];

    float bestv[8], secv[8];
    int   bestk[8];
#pragma unroll
    for (int i = 0; i < 8; ++i) { bestv[i] = 3.0e38f; secv[i] = 3.0e38f; bestk[i] = 0; }

    float a[8][8];
#pragma unroll
    for (int i = 0; i < 8; ++i)
#pragma unroll
        for (int j = 0; j < 8; ++j) a[i][j] = 0.f;

    int cur = 0;
    for (int ci = 0; ci < 128; ++ci) {           // ci = kt*16 + dc
        // ---- issue next-chunk loads (overlap with compute) ----
        float4 nx0, nx1, ne0, ne1;
        const bool have = (ci + 1 < 128);
        if (have) {
            int nkt = (ci + 1) >> 4, nd0 = ((ci + 1) & 15) * DC;
            const float* zp = z + (size_t)(r0 + scol) * D + nd0 + soff;
            nx0 = *(const float4*)zp; nx1 = *(const float4*)(zp + 4);
            const float* ep = emb + (size_t)(nkt * BN + scol) * D + nd0 + soff;
            ne0 = *(const float4*)ep; ne1 = *(const float4*)(ep + 4);
        }
        // ---- compute on current chunk ----
#pragma unroll
        for (int kk = 0; kk < DC; ++kk) {
            float4 xlo = *(const float4*)&xs_c[cur][kk][ty << 2];
            float4 xhi = *(const float4*)&xs_c[cur][kk][64 + (ty << 2)];
            float4 elo = *(const float4*)&es_c[cur][kk][tx << 2];
            float4 ehi = *(const float4*)&es_c[cur][kk][64 + (tx << 2)];
            float xr[8] = { xlo.x, xlo.y, xlo.z, xlo.w, xhi.x, xhi.y, xhi.z, xhi.w };
            float er[8] = { elo.x, elo.y, elo.z, elo.w, ehi.x, ehi.y, ehi.z, ehi.w };
#pragma unroll
            for (int i = 0; i < 8; ++i)
#pragma unroll
                for (int j = 0; j < 8; ++j)
                    a[i][j] = fmaf(xr[i], er[j], a[i][j]);
        }
        // ---- end of kt: score 8x8, reset acc ----
        if ((ci & 15) == 15) {
            int kt = ci >> 4;
#pragma unroll
            for (int j = 0; j < 8; ++j) {
                int c = (j < 4) ? (tx * 4 + j) : (64 + tx * 4 + j - 4);
                float se = se32[kt * BN + c];
#pragma unroll
                for (int i = 0; i < 8; ++i) {
                    float t = __fadd_rn(__fsub_rn(sxr[i], 2.0f * a[i][j]), se);
                    if (t < bestv[i]) { secv[i] = bestv[i]; bestv[i] = t; bestk[i] = kt * BN + c; }
                    else if (t < secv[i]) { secv[i] = t; }
                    a[i][j] = 0.f;
                }
            }
        }
        __syncthreads();                          // all reads of buf[cur] done
        if (have) {
            int nb = cur ^ 1;
            const float* af = (const float*)&nx0; const float* af1 = (const float*)&nx1;
            const float* bf = (const float*)&ne0; const float* bf1 = (const float*)&ne1;
#pragma unroll
            for (int e = 0; e < 4; ++e) {
                xs_c[nb][soff + e][scol]     = af[e];
                xs_c[nb][soff + 4 + e][scol] = af1[e];
                es_c[nb][soff + e][scol]     = bf[e];
                es_c[nb][soff + 4 + e][scol] = bf1[e];
            }
            cur = nb;
            __syncthreads();                      // staged data visible
        }
    }

    // ---- cross-thread top-2 reduce (overlay red arrays on chunk LDS) ----
    __syncthreads();
    float* red_val = (float*)&xs_c[0][0][0];          // 2048 floats
    float* red_sec = red_val + 2048;                  // 2048 floats (16.9KB ok)
    int*   red_idx = (int*)&es_c[0][0][0];            // 2048 ints
#pragma unroll
    for (int i = 0; i < 8; ++i) {
        int r = (i < 4) ? (ty * 4 + i) : (64 + ty * 4 + i - 4);
        red_val[r * 16 + tx] = bestv[i];
        red_sec[r * 16 + tx] = secv[i];
        red_idx[r * 16 + tx] = bestk[i];
    }
    __syncthreads();
    float row_b1 = 0.f;
    if (tid < BM) {
        int r = tid;
        float b1 = 3.0e38f; int k1 = 1 << 30; int t1 = 0;
#pragma unroll
        for (int t = 0; t < 16; ++t) {
            float v  = red_val[r * 16 + t];
            int   id = red_idx[r * 16 + t];
            if (v < b1 || (v == b1 && id < k1)) { b1 = v; k1 = id; t1 = t; }
        }
        float b2 = 3.0e38f;
#pragma unroll
        for (int t = 0; t < 16; ++t) {
            float v = (t == t1) ? red_sec[r * 16 + t] : red_val[r * 16 + t];
            if (v < b2) b2 = v;
        }
        code_of_row[r] = k1;
        out_idx1[r0 + r] = (float)k1;
        out_idx2[r0 + r] = (float)k1;
        row_b1 = b1;                               // ||x - e_k1||^2 (f32 chain)
        if (b2 - b1 <= MARGIN) {
            int slot = atomicAdd(cnt, 1);
            if (slot < CAP) rowlist[slot] = r0 + r;
        }
    }
    // loss: sum winner distances (f32-chain t; error ~6e-5 on ~256 — negligible)
#pragma unroll
    for (int off = 32; off > 0; off >>= 1) row_b1 += __shfl_down(row_b1, off);
    if (tid < BM && (tid & 63) == 0) atomicAdd(acc, (double)row_b1);
    __syncthreads();

    // ---- gather z_q ----
    {
        int r = tid >> 1;                          // 0..127
        int h = (tid & 1) * 128;                   // row half
        const float* ep = emb + (size_t)code_of_row[r] * D + h;
        float* op = out_zq + (size_t)(r0 + r) * D + h;
#pragma unroll
        for (int q = 0; q < 32; ++q)
            *(float4*)(op + 4 * q) = *(const float4*)(ep + 4 * q);
    }
}

// ------------------------------------------------------------- rescore ----
// Exact np chain (f64 dot -> f32 round) for flagged rows; one wave per row.
__global__ __launch_bounds__(256) void vq_rescore(const float* __restrict__ z,
                                                  const float* __restrict__ emb,
                                                  const float* __restrict__ se32,
                                                  float* __restrict__ out_idx1,
                                                  float* __restrict__ out_idx2,
                                                  const int* __restrict__ rowlist,
                                                  const int* __restrict__ cnt) {
    int gw   = (blockIdx.x * blockDim.x + threadIdx.x) >> 6;
    int nw   = (gridDim.x * blockDim.x) >> 6;
    int lane = threadIdx.x & 63;
    int n = *cnt; if (n > CAP) n = CAP;
    for (int li = gw; li < n; li += nw) {
        int row = rowlist[li];
        const float*  x  = z + (size_t)row * D;
        const float4* xp = (const float4*)x;
        float sx = np_sumsq_256(x, 1);
        float bt = 3.0e38f; int bk = 1 << 30;
        for (int c = 0; c < 16; ++c) {
            int k = c * 64 + lane;
            const float4* ep = (const float4*)(emb + (size_t)k * D);
            double s = 0.0;
#pragma unroll 8
            for (int q = 0; q < 64; ++q) {
                float4 ev = ep[q];
                float4 xv = xp[q];
                s = fma((double)xv.x, (double)ev.x, s);
                s = fma((double)xv.y, (double)ev.y, s);
                s = fma((double)xv.z, (double)ev.z, s);
                s = fma((double)xv.w, (double)ev.w, s);
            }
            float g = (float)s;
            float t = __fadd_rn(__fsub_rn(sx, 2.0f * g), se32[k]);
            if (t < bt) { bt = t; bk = k; }        // c ascending: lowest k on tie
        }
#pragma unroll
        for (int off = 32; off > 0; off >>= 1) {
            float ot = __shfl_xor(bt, off);
            int   ok = __shfl_xor(bk, off);
            if (ot < bt || (ot == bt && ok < bk)) { bt = ot; bk = ok; }
        }
        if (lane == 0) { out_idx1[row] = (float)bk; out_idx2[row] = (float)bk; }
    }
}

// ------------------------------------------------------------ finalize ----
__global__ void vq_finalize(const double* __restrict__ acc,
                            float* __restrict__ l1, float* __restrict__ l2) {
    double m = *acc / (double)ZQ_N;
    float v = (float)(1.25 * m);
    *l1 = v; *l2 = v;
}

// -------------------------------------------------------------- launch ----
extern "C" void kernel_launch(void* const* d_in, const int* in_sizes, int n_in,
                              void* d_out, int out_size, void* d_ws, size_t ws_size,
                              hipStream_t stream) {
    const float* z   = (const float*)d_in[0];
    const float* emb = (const float*)d_in[1];
    float* out = (float*)d_out;

    float* out_zq    = out;
    float* out_loss1 = out + ZQ_N;
    float* out_idx1  = out + ZQ_N + 1;
    size_t osz = (size_t)out_size;
    float* out_idx2  = out + (osz - (size_t)NROWS);      // == out_idx1 (dense)
    float* out_loss2 = out + (osz - (size_t)NROWS - 1);

    float*  se32    = (float*)d_ws;                      // 4 KB
    double* acc     = (double*)((char*)d_ws + 4096);     // 8 B
    int*    cnt     = (int*)((char*)d_ws + 4104);        // 4 B
    int*    rowlist = (int*)((char*)d_ws + 8192);        // 128 KB

    vq_prep<<<4, 256, 0, stream>>>(emb, se32, acc, cnt);
    vq_main<<<NROWS / BM, 256, 0, stream>>>(z, emb, se32, out_zq, out_idx1,
                                            out_idx2, acc, cnt, rowlist);
    vq_rescore<<<512, 256, 0, stream>>>(z, emb, se32, out_idx1, out_idx2,
                                        rowlist, cnt);
    vq_finalize<<<1, 1, 0, stream>>>(acc, out_loss1, out_loss2);
}